// Round 1
// baseline (28.119 us; speedup 1.0000x reference)
//
#include <hip/hip_runtime.h>

// LIF neuron: v' = v*TAU + x + r; s = (v'>0); v = s ? 0 : v'
// T=100 sequential steps, B*N = 131072 independent chains.
// Memory-bound streaming: ~157 MB per call.

#define TAU 0.5f

__global__ __launch_bounds__(256) void lif_scan_kernel(
    const float2* __restrict__ inp,
    const float2* __restrict__ rec,
    float2* __restrict__ out,
    int n2,   // elements-per-timestep / 2  (B*N/2)
    int T)
{
    const int i = blockIdx.x * blockDim.x + threadIdx.x;
    if (i >= n2) return;

    float vx = 0.0f, vy = 0.0f;

    #pragma unroll 4
    for (int t = 0; t < T; ++t) {
        const size_t off = (size_t)t * (size_t)n2 + (size_t)i;
        float2 x = inp[off];
        float2 r = rec[off];

        // Only multiply is by 0.5 (exact), so fp-contract can't change the
        // rounded result vs numpy's (v*0.5 + x) + r.
        vx = vx * TAU + x.x + r.x;
        vy = vy * TAU + x.y + r.y;

        float2 s;
        s.x = (vx > 0.0f) ? 1.0f : 0.0f;
        s.y = (vy > 0.0f) ? 1.0f : 0.0f;

        // hard reset where spiked
        vx = (vx > 0.0f) ? 0.0f : vx;
        vy = (vy > 0.0f) ? 0.0f : vy;

        out[off] = s;
    }
}

extern "C" void kernel_launch(void* const* d_in, const int* in_sizes, int n_in,
                              void* d_out, int out_size, void* d_ws, size_t ws_size,
                              hipStream_t stream) {
    const float* inp = (const float*)d_in[0];
    const float* rec = (const float*)d_in[1];
    float* out = (float*)d_out;

    const int T = 100;
    const int per_t = in_sizes[0] / T;   // B*N = 131072
    const int n2 = per_t / 2;            // 65536 float2 lanes

    const int block = 256;
    const int grid = (n2 + block - 1) / block;   // 256 blocks -> 1 per CU

    lif_scan_kernel<<<grid, block, 0, stream>>>(
        (const float2*)inp, (const float2*)rec, (float2*)out, n2, T);
}